// Round 7
// baseline (262.867 us; speedup 1.0000x reference)
//
#include <hip/hip_runtime.h>
#include <hip/hip_cooperative_groups.h>

namespace cg = cooperative_groups;

#define N_NODES 25000
#define N_EDGES 100000
#define NPAD 25024     // 391*64
#define CH 280
#define HC 1120        // NH*CH
#define CAP 32         // fixed CSR capacity; P(deg>32)~1e-18 for Binom(1e5,1/25e3)
#define MAXGRID 512

typedef unsigned int uint;
typedef unsigned short ushort;
typedef __attribute__((ext_vector_type(8))) short short8;   // 8 bf16 (4 VGPRs)
typedef __attribute__((ext_vector_type(4))) float f32x4;    // MFMA C/D frag

// factor buffer layout (floats)
#define FAC_A 0        // [4][16][16] = 1024
#define FAC_B 1024     // [4][16][6]  = 384
#define FAC_C 1408     // [4][16]     = 64
#define FAC_D 1472     // [4][16]     = 64
#define FAC_F 1536     // [4][6]      = 24
#define FAC_G 1560     // [4]         = 4
#define FAC_TOTAL 1564

// V row layout (128 bf16 per node):
//  [h*24 + j] j=0..22 : attn aggregates for head h (j=23 pad=0)
//  [96..111] : x (bf16)   [112] : 1.0   [113..127] : 0
#define WC_K 128

// P1 virtual-block section bounds
#define S_FAC_END  25    // 25*256 = 6400 >= 1564*4 lanes
#define S_WC_END   57    // 32 blocks x 4 waves = 128 rows (incl. zero rows)
#define S_W2_END   58
#define S_FILL_END 449   // 391 blocks >= 100000 edges
#define S_TOTAL    547   // + 98 vbskip blocks

struct KArgs {
  const float *x; const int *ei; const float *ea;
  const float *Wq, *bq, *Wk, *bk, *Wv, *bv, *We, *Wskip, *bskip;
  const float *W1, *b1v, *W2, *b2, *W3, *b3;
  float *out;
  float *fac; ushort *Wct; int *cursor; ushort *W2tg; ushort *Vb; float *erec;
};

__device__ __forceinline__ ushort f2bf(float f) {
  union { float f; uint u; } c; c.f = f;
  uint u = c.u + 0x7FFFu + ((c.u >> 16) & 1u);   // RNE
  return (ushort)(u >> 16);
}

__global__ __launch_bounds__(256, 2) void mega_kernel(KArgs A) {
  cg::grid_group gg = cg::this_grid();
  __shared__ ushort Wcs[64 * 136];   // Wc^T staged, row stride 136
  __shared__ ushort W2ts[16 * 72];   // W2^T staged, row stride 72
  __shared__ ushort h1b[64 * 72];    // h1 bf16, row stride 72
  __shared__ float  h2s[64 * 17];    // h2 fp32
  const int nblk = gridDim.x;
  const int tid = threadIdx.x;

  // ===== P0: zero cursor =====
  for (int g = blockIdx.x * 256 + tid; g < N_NODES; g += nblk * 256)
    A.cursor[g] = 0;
  gg.sync();

  // ===== P1: factors + Wc^T + W2^T + capacity-CSR fill + Vb skip rows =====
  for (int b = blockIdx.x; b < S_TOTAL; b += nblk) {
    if (b < S_FAC_END) {
      // ---- factors: A_h=Wq_h Wk_h^T, B=Wq We^T, c=Wq bk, d=Wk bq, f=We bq, g=bq.bk
      int t4 = b * 256 + tid;
      int q = t4 >> 2, li = t4 & 3;
      if (q < FAC_TOTAL) {
        const float *pa, *pb;
        if (q < FAC_B) {
          int h = q >> 8, f = (q >> 4) & 15, g = q & 15;
          pa = A.Wq + f * HC + h * CH; pb = A.Wk + g * HC + h * CH;
        } else if (q < FAC_C) {
          int u = q - FAC_B; int h = u / 96, v2 = u % 96, f = v2 / 6, j = v2 % 6;
          pa = A.Wq + f * HC + h * CH; pb = A.We + j * HC + h * CH;
        } else if (q < FAC_D) {
          int u = q - FAC_C; int h = u >> 4, f = u & 15;
          pa = A.Wq + f * HC + h * CH; pb = A.bk + h * CH;
        } else if (q < FAC_F) {
          int u = q - FAC_D; int h = u >> 4, g = u & 15;
          pa = A.Wk + g * HC + h * CH; pb = A.bq + h * CH;
        } else if (q < FAC_G) {
          int u = q - FAC_F; int h = u / 6, j = u % 6;
          pa = A.We + j * HC + h * CH; pb = A.bq + h * CH;
        } else {
          int h = q - FAC_G;
          pa = A.bq + h * CH; pb = A.bk + h * CH;
        }
        float acc = 0.f;
        int c0 = li * 70;
        for (int c = c0; c < c0 + 70; ++c) acc = fmaf(pa[c], pb[c], acc);
        acc += __shfl_xor(acc, 1);
        acc += __shfl_xor(acc, 2);
        if (li == 0) A.fac[q] = acc;
      }
    } else if (b < S_WC_END) {
      // ---- Wc^T[k][r] bf16 = (W_all @ W1)[r][k]; wave per row (128 rows incl zeros)
      int wid = tid >> 6;
      int r = __builtin_amdgcn_readfirstlane((b - S_FAC_END) * 4 + wid);
      int k = tid & 63;
      float v = 0.f;
      bool wz = true;
      if (r < 113) {
        const float* w = nullptr;
        float scale = 1.f;
        bool zero = false;
        if (r < 96) {
          int h = r / 24, j = r % 24;
          if (j == 23) zero = true;
          else {
            if (j < 16) w = A.Wv + j * HC + h * CH;
            else if (j < 22) w = A.We + (j - 16) * HC + h * CH;
            else w = A.bv + h * CH;
            scale = 0.25f;   // mean over 4 heads
          }
        } else if (r < 112) {
          w = A.Wskip + (r - 96) * CH;
        } else {
          w = A.bskip;
        }
        if (!zero) {
          float acc = 0.f;
          for (int c = 0; c < CH; ++c) acc = fmaf(w[c], A.W1[c * 64 + k], acc);
          v = acc * scale;
          if (r == 112) v += A.b1v[k];   // fold b1 into const row
          wz = false;
        }
      }
      A.Wct[k * WC_K + r] = wz ? (ushort)0 : f2bf(v);
    } else if (b < S_W2_END) {
      // ---- W2^T bf16 [16][64]
      for (int t = tid; t < 1024; t += 256) {
        int m2 = t >> 6, k = t & 63;
        A.W2tg[m2 * 64 + k] = f2bf(A.W2[(size_t)k * 16 + m2]);
      }
    } else if (b < S_FILL_END) {
      // ---- capacity-CSR fill: slot = atomicAdd(cursor[dst])
      int e = (b - S_W2_END) * 256 + tid;
      if (e < N_EDGES) {
        int src = A.ei[e];
        int dst = A.ei[N_EDGES + e];
        int pos = atomicAdd(&A.cursor[dst], 1);
        if (pos < CAP) {
          const float2* s2 = (const float2*)(A.ea + (size_t)e * 6);
          float2 e01 = s2[0], e23 = s2[1], e45 = s2[2];
          int4 w0;
          w0.x = src;
          w0.y = __float_as_int(e01.x); w0.z = __float_as_int(e01.y);
          w0.w = __float_as_int(e23.x);
          float4 w1 = make_float4(e23.y, e45.x, e45.y, 0.f);
          float* dstp = A.erec + ((size_t)dst * CAP + pos) * 8;
          *(int4*)dstp = w0;
          *(float4*)(dstp + 4) = w1;
        }
      }
    } else {
      // ---- Vb skip-path rows [96..127]: bf16 x, const 1.0, zeros
      int n = (b - S_FILL_END) * 256 + tid;
      if (n < N_NODES) {
        const float4* x4 = (const float4*)(A.x + (size_t)n * 16);
        float xv[16];
#pragma unroll
        for (int i = 0; i < 4; ++i) {
          float4 q = x4[i];
          xv[4 * i] = q.x; xv[4 * i + 1] = q.y; xv[4 * i + 2] = q.z; xv[4 * i + 3] = q.w;
        }
        uint pk[8];
#pragma unroll
        for (int i = 0; i < 8; ++i)
          pk[i] = (uint)f2bf(xv[2 * i]) | ((uint)f2bf(xv[2 * i + 1]) << 16);
        int4* vp = (int4*)(A.Vb + (size_t)n * WC_K + 96);
        int4 s0, s1, s2, s3;
        s0.x = (int)pk[0]; s0.y = (int)pk[1]; s0.z = (int)pk[2]; s0.w = (int)pk[3];
        s1.x = (int)pk[4]; s1.y = (int)pk[5]; s1.z = (int)pk[6]; s1.w = (int)pk[7];
        s2.x = (int)0x3F80u; s2.y = 0; s2.z = 0; s2.w = 0;   // bf16(1.0) + zeros
        s3.x = 0; s3.y = 0; s3.z = 0; s3.w = 0;
        vp[0] = s0; vp[1] = s1; vp[2] = s2; vp[3] = s3;
      }
    }
  }
  gg.sync();

  // ===== P2: attn — 4 lanes per (node, head), inline v from fac (s_loads) =====
  const float RS = 0.05976143046671968f;  // 1/sqrt(280)
  for (int vu = blockIdx.x; vu < 391 * 4; vu += nblk) {
    int h = vu & 3, bx = vu >> 2;
    int wid = tid >> 6, lane = tid & 63;
    int sub = lane >> 2, half = lane & 3;
    int n = (bx * 4 + wid) * 16 + sub;
    if (n < N_NODES) {
      float xv[16];
      {
        const float4* x4 = (const float4*)(A.x + (size_t)n * 16);
#pragma unroll
        for (int i = 0; i < 4; ++i) {
          float4 q = x4[i];
          xv[4 * i] = q.x; xv[4 * i + 1] = q.y; xv[4 * i + 2] = q.z; xv[4 * i + 3] = q.w;
        }
      }
      const float* Af = A.fac + FAC_A + h * 256;
      const float* Bf = A.fac + FAC_B + h * 96;
      const float* cf = A.fac + FAC_C + h * 16;
      const float* df = A.fac + FAC_D + h * 16;
      const float* ff = A.fac + FAC_F + h * 6;
      const float  gf = A.fac[FAC_G + h];
      float va[16];   // A^T x_dst + d_h
#pragma unroll
      for (int g = 0; g < 16; ++g) {
        float a = df[g];
#pragma unroll
        for (int f = 0; f < 16; ++f) a = fmaf(xv[f], Af[f * 16 + g], a);
        va[g] = a;
      }
      float ve[6];    // B^T x_dst + f_h
#pragma unroll
      for (int j = 0; j < 6; ++j) {
        float a = ff[j];
#pragma unroll
        for (int f = 0; f < 16; ++f) a = fmaf(xv[f], Bf[f * 6 + j], a);
        ve[j] = a;
      }
      float v22 = gf;
#pragma unroll
      for (int f = 0; f < 16; ++f) v22 = fmaf(xv[f], cf[f], v22);

      int dg = A.cursor[n];
      if (dg > CAP) dg = CAP;
      float m = -1e30f, den = 0.f;
      float Sx[16];
      float Sa[6];
#pragma unroll
      for (int f = 0; f < 16; ++f) Sx[f] = 0.f;
#pragma unroll
      for (int j = 0; j < 6; ++j) Sa[j] = 0.f;
      for (int q2 = half; q2 < dg; q2 += 4) {
        const float* er = A.erec + ((size_t)n * CAP + q2) * 8;
        int4 ra = *(const int4*)er;
        float4 rb = *(const float4*)(er + 4);
        int s = ra.x;
        const float4* xs4 = (const float4*)(A.x + (size_t)s * 16);
        float4 a0 = xs4[0], a1 = xs4[1], a2 = xs4[2], a3 = xs4[3];
        float xs[16] = {a0.x, a0.y, a0.z, a0.w, a1.x, a1.y, a1.z, a1.w,
                        a2.x, a2.y, a2.z, a2.w, a3.x, a3.y, a3.z, a3.w};
        float eav[6] = {__int_as_float(ra.y), __int_as_float(ra.z),
                        __int_as_float(ra.w), rb.x, rb.y, rb.z};
        float alpha = v22;
#pragma unroll
        for (int f = 0; f < 16; ++f) alpha = fmaf(va[f], xs[f], alpha);
#pragma unroll
        for (int j = 0; j < 6; ++j) alpha = fmaf(ve[j], eav[j], alpha);
        alpha *= RS;
        float nm = fmaxf(m, alpha);
        float sc = __expf(m - nm);
        float w = __expf(alpha - nm);
        den = den * sc + w;
#pragma unroll
        for (int f = 0; f < 16; ++f) Sx[f] = fmaf(Sx[f], sc, w * xs[f]);
#pragma unroll
        for (int j = 0; j < 6; ++j) Sa[j] = fmaf(Sa[j], sc, w * eav[j]);
        m = nm;
      }
      // merge 4 lanes (xor 1, then 2)
#pragma unroll
      for (int d = 1; d <= 2; d <<= 1) {
        float mo  = __shfl_xor(m, d);
        float dno = __shfl_xor(den, d);
        float mm = fmaxf(m, mo);
        float sa = __expf(m - mm);
        float sb = __expf(mo - mm);
        den = den * sa + dno * sb;
#pragma unroll
        for (int f = 0; f < 16; ++f) {
          float so = __shfl_xor(Sx[f], d);
          Sx[f] = Sx[f] * sa + so * sb;
        }
#pragma unroll
        for (int j = 0; j < 6; ++j) {
          float so = __shfl_xor(Sa[j], d);
          Sa[j] = Sa[j] * sa + so * sb;
        }
        m = mm;
      }
      if (half == 0) {
        float inv = 1.f / (den + 1e-16f);
        float outv[24];
#pragma unroll
        for (int f = 0; f < 16; ++f) outv[f] = Sx[f] * inv;
#pragma unroll
        for (int j = 0; j < 6; ++j) outv[16 + j] = Sa[j] * inv;
        outv[22] = den * inv;   // sum of attn (1 unless isolated node)
        outv[23] = 0.f;
        uint pk[12];
#pragma unroll
        for (int i = 0; i < 12; ++i)
          pk[i] = (uint)f2bf(outv[2 * i]) | ((uint)f2bf(outv[2 * i + 1]) << 16);
        int4* vp = (int4*)(A.Vb + (size_t)n * WC_K + h * 24);
        int4 s0, s1, s2;
        s0.x = (int)pk[0]; s0.y = (int)pk[1]; s0.z = (int)pk[2]; s0.w = (int)pk[3];
        s1.x = (int)pk[4]; s1.y = (int)pk[5]; s1.z = (int)pk[6]; s1.w = (int)pk[7];
        s2.x = (int)pk[8]; s2.y = (int)pk[9]; s2.z = (int)pk[10]; s2.w = (int)pk[11];
        vp[0] = s0; vp[1] = s1; vp[2] = s2;
      }
    }
  }
  gg.sync();

  // ===== P3: mlp MFMA GEMM, one 64-node tile per virtual block =====
  for (int tile = blockIdx.x; tile < 391; tile += nblk) {
    int wid = tid >> 6, lane = tid & 63;
    int col15 = lane & 15, quad = lane >> 4;
    {  // stage Wc^T: 64 rows x 128 bf16 -> stride 136
      int row = tid >> 2, seg = tid & 3;
      const ushort* src = A.Wct + row * 128 + seg * 32;
      ushort* dst = Wcs + row * 136 + seg * 32;
#pragma unroll
      for (int i = 0; i < 4; ++i)
        *(int4*)(dst + i * 8) = *(const int4*)(src + i * 8);
    }
    if (tid < 128) {  // stage W2^T: 16 rows x 64 bf16 -> stride 72
      int row = tid >> 3, seg = tid & 7;
      *(int4*)(W2ts + row * 72 + seg * 8) = *(const int4*)(A.W2tg + row * 64 + seg * 8);
    }
    __syncthreads();
    // ---- layer 1 GEMM: wave handles 16 nodes x 64 cols (4 C-tiles)
    int node = tile * 64 + wid * 16 + col15;
    f32x4 acc[4];
#pragma unroll
    for (int T = 0; T < 4; ++T) acc[T] = (f32x4){0.f, 0.f, 0.f, 0.f};
#pragma unroll
    for (int kk = 0; kk < 4; ++kk) {
      int k0 = kk * 32;
      short8 a = *(const short8*)(A.Vb + (size_t)node * WC_K + k0 + quad * 8);
#pragma unroll
      for (int T = 0; T < 4; ++T) {
        short8 bfr = *(const short8*)(Wcs + (T * 16 + col15) * 136 + k0 + quad * 8);
        acc[T] = __builtin_amdgcn_mfma_f32_16x16x32_bf16(a, bfr, acc[T], 0, 0, 0);
      }
    }
#pragma unroll
    for (int T = 0; T < 4; ++T) {
#pragma unroll
      for (int r = 0; r < 4; ++r) {
        int nloc = wid * 16 + quad * 4 + r;
        int c = T * 16 + col15;
        h1b[nloc * 72 + c] = f2bf(fmaxf(acc[T][r], 0.f));
      }
    }
    __syncthreads();
    // ---- layer 2 GEMM: h2[16 nodes x 16] per wave, K=64 -> 2 mfma
    float b2v = A.b2[col15];
    f32x4 acc2 = (f32x4){0.f, 0.f, 0.f, 0.f};
#pragma unroll
    for (int kk = 0; kk < 2; ++kk) {
      int k0 = kk * 32;
      short8 a2 = *(const short8*)(h1b + (wid * 16 + col15) * 72 + k0 + quad * 8);
      short8 bf2 = *(const short8*)(W2ts + col15 * 72 + k0 + quad * 8);
      acc2 = __builtin_amdgcn_mfma_f32_16x16x32_bf16(a2, bf2, acc2, 0, 0, 0);
    }
#pragma unroll
    for (int r = 0; r < 4; ++r) {
      int nloc = wid * 16 + quad * 4 + r;
      h2s[nloc * 17 + col15] = fmaxf(acc2[r] + b2v, 0.f);
    }
    __syncthreads();
    // ---- layer 3 + softmax: one thread per node
    if (tid < 64) {
      int n = tile * 64 + tid;
      if (n < N_NODES) {
        float hv[16];
#pragma unroll
        for (int j = 0; j < 16; ++j) hv[j] = h2s[tid * 17 + j];
        float lg[6];
        float mx = -1e30f;
#pragma unroll
        for (int o = 0; o < 6; ++o) {
          float a = A.b3[o];
#pragma unroll
          for (int j = 0; j < 16; ++j) a = fmaf(hv[j], A.W3[j * 6 + o], a);
          lg[o] = a; mx = fmaxf(mx, a);
        }
        float s = 0.f;
#pragma unroll
        for (int o = 0; o < 6; ++o) { lg[o] = __expf(lg[o] - mx); s += lg[o]; }
        float inv = 1.f / s;
        float2* o2 = (float2*)(A.out + (size_t)n * 6);
        o2[0] = make_float2(lg[0] * inv, lg[1] * inv);
        o2[1] = make_float2(lg[2] * inv, lg[3] * inv);
        o2[2] = make_float2(lg[4] * inv, lg[5] * inv);
      }
    }
    __syncthreads();   // protect LDS before next tile iteration
  }
}

extern "C" void kernel_launch(void* const* d_in, const int* in_sizes, int n_in,
                              void* d_out, int out_size, void* d_ws, size_t ws_size,
                              hipStream_t stream) {
  (void)in_sizes; (void)n_in; (void)out_size; (void)ws_size;
  char* ws = (char*)d_ws;
  size_t off = 0;
  auto alloc = [&](size_t bytes) {
    void* p = ws + off;
    off = (off + bytes + 255) & ~(size_t)255;
    return p;
  };
  KArgs A;
  A.x     = (const float*)d_in[0];
  A.ei    = (const int*)d_in[1];
  A.ea    = (const float*)d_in[2];
  A.Wq    = (const float*)d_in[3];
  A.bq    = (const float*)d_in[4];
  A.Wk    = (const float*)d_in[5];
  A.bk    = (const float*)d_in[6];
  A.Wv    = (const float*)d_in[7];
  A.bv    = (const float*)d_in[8];
  A.We    = (const float*)d_in[9];
  A.Wskip = (const float*)d_in[10];
  A.bskip = (const float*)d_in[11];
  A.W1    = (const float*)d_in[12];
  A.b1v   = (const float*)d_in[13];
  A.W2    = (const float*)d_in[14];
  A.b2    = (const float*)d_in[15];
  A.W3    = (const float*)d_in[16];
  A.b3    = (const float*)d_in[17];
  A.out   = (float*)d_out;
  A.fac    = (float*)alloc(FAC_TOTAL * 4);
  A.Wct    = (ushort*)alloc(64 * WC_K * 2);
  A.cursor = (int*)alloc(N_NODES * 4);
  A.W2tg   = (ushort*)alloc(16 * 64 * 2);
  A.Vb     = (ushort*)alloc((size_t)NPAD * WC_K * 2);
  A.erec   = (float*)alloc((size_t)N_NODES * CAP * 8 * 4);

  int maxB = 0;
  if (hipOccupancyMaxActiveBlocksPerMultiprocessor(&maxB, mega_kernel, 256, 0)
          != hipSuccess || maxB < 1)
    maxB = 1;
  int grid = maxB * 256;            // 256 CUs
  if (grid > MAXGRID) grid = MAXGRID;
  void* kp[] = {(void*)&A};
  hipLaunchCooperativeKernel((const void*)mega_kernel, dim3(grid), dim3(256),
                             kp, 0, stream);
}

// Round 8
// 118.090 us; speedup vs baseline: 2.2260x; 2.2260x over previous
//
#include <hip/hip_runtime.h>

#define N_NODES 25000
#define N_EDGES 100000
#define CH 280
#define HC 1120        // NH*CH
#define CAP 32         // fixed CSR capacity; P(deg>32)~1e-18 for Binom(1e5,1/25e3)

typedef unsigned int uint;
typedef unsigned short ushort;
typedef __attribute__((ext_vector_type(8))) short short8;   // 8 bf16 (4 VGPRs)
typedef __attribute__((ext_vector_type(4))) float f32x4;    // MFMA C/D frag

// factor buffer layout (floats)
#define FAC_A 0        // [4][16][16] = 1024
#define FAC_B 1024     // [4][16][6]  = 384
#define FAC_C 1408     // [4][16]     = 64
#define FAC_D 1472     // [4][16]     = 64
#define FAC_F 1536     // [4][6]      = 24
#define FAC_G 1560     // [4]         = 4
#define FAC_TOTAL 1564

// V row layout (128 bf16 per node), LDS-only in the fused kernel:
//  [h*24 + j] j=0..22 : attn aggregates for head h (j=23 pad=0)
//  [96..111] : x (bf16)   [112] : 1.0   [113..127] : 0
// Wc^T (bf16 [64 cols][128 rows]) matches; row112 col k = bskip·W1_k + b1[k].
#define WC_K 128

// prep block ranges
#define P_FAC_END  25    // 25*256 = 6400 >= 1564*4 lanes
#define P_WC_END   57    // 32 blocks x 4 waves = 128 rows (incl. zero rows)
#define P_W2_END   58
#define P_TOTAL    449   // + 391 fill blocks

__device__ __forceinline__ ushort f2bf(float f) {
  union { float f; uint u; } c; c.f = f;
  uint u = c.u + 0x7FFFu + ((c.u >> 16) & 1u);   // RNE
  return (ushort)(u >> 16);
}

// ---------------------------------------------------------------------------
// prep: factors + Wc^T bf16 (all 128 rows, incl zeros) + W2^T bf16 +
// capacity-CSR fill. Plain dispatch; no grid-stride, no sync.
// ---------------------------------------------------------------------------
__global__ __launch_bounds__(256) void prep_kernel(
    const float* __restrict__ Wq, const float* __restrict__ Wk,
    const float* __restrict__ We, const float* __restrict__ bq,
    const float* __restrict__ bk, float* __restrict__ fac,
    const float* __restrict__ Wv, const float* __restrict__ bv,
    const float* __restrict__ Wskip, const float* __restrict__ bskip,
    const float* __restrict__ W1, const float* __restrict__ b1,
    ushort* __restrict__ Wct,
    const float* __restrict__ W2, ushort* __restrict__ W2tg,
    const int* __restrict__ ei, const float* __restrict__ ea,
    int* __restrict__ cursor, float* __restrict__ erec) {
  int b = blockIdx.x;
  int tid = threadIdx.x;
  if (b < P_FAC_END) {
    // ---- factors: A_h=Wq_h Wk_h^T, B=Wq We^T, c=Wq bk, d=Wk bq, f=We bq, g=bq.bk
    int t4 = b * 256 + tid;
    int q = t4 >> 2, li = t4 & 3;
    if (q >= FAC_TOTAL) return;
    const float *pa, *pb;
    if (q < FAC_B) {
      int h = q >> 8, f = (q >> 4) & 15, g = q & 15;
      pa = Wq + f * HC + h * CH; pb = Wk + g * HC + h * CH;
    } else if (q < FAC_C) {
      int u = q - FAC_B; int h = u / 96, v2 = u % 96, f = v2 / 6, j = v2 % 6;
      pa = Wq + f * HC + h * CH; pb = We + j * HC + h * CH;
    } else if (q < FAC_D) {
      int u = q - FAC_C; int h = u >> 4, f = u & 15;
      pa = Wq + f * HC + h * CH; pb = bk + h * CH;
    } else if (q < FAC_F) {
      int u = q - FAC_D; int h = u >> 4, g = u & 15;
      pa = Wk + g * HC + h * CH; pb = bq + h * CH;
    } else if (q < FAC_G) {
      int u = q - FAC_F; int h = u / 6, j = u % 6;
      pa = We + j * HC + h * CH; pb = bq + h * CH;
    } else {
      int h = q - FAC_G;
      pa = bq + h * CH; pb = bk + h * CH;
    }
    float acc = 0.f;
    int c0 = li * 70;
    for (int c = c0; c < c0 + 70; ++c) acc = fmaf(pa[c], pb[c], acc);
    acc += __shfl_xor(acc, 1);
    acc += __shfl_xor(acc, 2);
    if (li == 0) fac[q] = acc;
  } else if (b < P_WC_END) {
    // ---- Wc^T[k][r] bf16; one wave per row r (0..127, zero rows written too)
    int wid = tid >> 6;
    int r = __builtin_amdgcn_readfirstlane((b - P_FAC_END) * 4 + wid);
    int k = tid & 63;
    float v = 0.f;
    bool wz = true;
    if (r < 113) {
      const float* w = nullptr;
      float scale = 1.f;
      bool zero = false;
      if (r < 96) {
        int h = r / 24, j = r % 24;
        if (j == 23) zero = true;
        else {
          if (j < 16) w = Wv + j * HC + h * CH;
          else if (j < 22) w = We + (j - 16) * HC + h * CH;
          else w = bv + h * CH;
          scale = 0.25f;   // mean over 4 heads
        }
      } else if (r < 112) {
        w = Wskip + (r - 96) * CH;
      } else {
        w = bskip;
      }
      if (!zero) {
        float acc = 0.f;
        for (int c = 0; c < CH; ++c) acc = fmaf(w[c], W1[c * 64 + k], acc);
        v = acc * scale;
        if (r == 112) v += b1[k];   // fold b1 into const row
        wz = false;
      }
    }
    Wct[k * WC_K + r] = wz ? (ushort)0 : f2bf(v);
  } else if (b < P_W2_END) {
    // ---- W2^T bf16 [16][64]
    for (int t = tid; t < 1024; t += 256) {
      int m2 = t >> 6, k = t & 63;
      W2tg[m2 * 64 + k] = f2bf(W2[(size_t)k * 16 + m2]);
    }
  } else {
    // ---- capacity-CSR fill: slot = atomicAdd(cursor[dst])
    int e = (b - P_W2_END) * 256 + tid;
    if (e >= N_EDGES) return;
    int src = ei[e];
    int dst = ei[N_EDGES + e];
    int pos = atomicAdd(&cursor[dst], 1);
    if (pos >= CAP) return;
    const float2* s2 = (const float2*)(ea + (size_t)e * 6);
    float2 e01 = s2[0], e23 = s2[1], e45 = s2[2];
    int4 w0;
    w0.x = src;
    w0.y = __float_as_int(e01.x); w0.z = __float_as_int(e01.y);
    w0.w = __float_as_int(e23.x);
    float4 w1 = make_float4(e23.y, e45.x, e45.y, 0.f);
    float* dstp = erec + ((size_t)dst * CAP + pos) * 8;
    *(int4*)dstp = w0;
    *(float4*)(dstp + 4) = w1;
  }
}

// ---------------------------------------------------------------------------
// fused attn+mlp: one block = one 64-node tile. Wave h (=wid) handles head h
// (fac via s_loads); lane = node-in-tile. Each lane runs the full edge loop
// with online softmax and writes its 24-entry V segment to LDS. Wave 0 also
// writes the skip rows (bf16 x, const 1, zeros) from registers. Then the
// 2-layer MFMA MLP reads V from LDS — no global V round-trip.
// ---------------------------------------------------------------------------
__global__ __launch_bounds__(256, 2) void fused_kernel(
    const float* __restrict__ x, const float* __restrict__ fac,
    const float* __restrict__ erec, const int* __restrict__ cursor,
    const ushort* __restrict__ Wct, const ushort* __restrict__ W2tg,
    const float* __restrict__ b2, const float* __restrict__ W3,
    const float* __restrict__ b3, float* __restrict__ out) {
  __shared__ ushort Vls[64 * 136];   // V tile, row stride 136
  __shared__ ushort Wcs[64 * 136];   // Wc^T staged, row stride 136
  __shared__ ushort W2ts[16 * 72];   // W2^T staged, row stride 72
  __shared__ ushort h1b[64 * 72];    // h1 bf16, row stride 72
  __shared__ float  h2s[64 * 17];    // h2 fp32
  const float RS = 0.05976143046671968f;  // 1/sqrt(280)
  int tid = threadIdx.x;
  int wid = tid >> 6, lane = tid & 63;
  int h = __builtin_amdgcn_readfirstlane(wid);

  {  // stage Wc^T: 64 rows x 128 bf16 -> stride 136
    int row = tid >> 2, seg = tid & 3;
    const ushort* src = Wct + row * 128 + seg * 32;
    ushort* dst = Wcs + row * 136 + seg * 32;
#pragma unroll
    for (int i = 0; i < 4; ++i)
      *(int4*)(dst + i * 8) = *(const int4*)(src + i * 8);
  }
  if (tid < 128) {  // stage W2^T: 16 rows x 64 bf16 -> stride 72
    int row = tid >> 3, seg = tid & 7;
    *(int4*)(W2ts + row * 72 + seg * 8) = *(const int4*)(W2tg + row * 64 + seg * 8);
  }

  // ===== attn: lane = node, wave = head =====
  int n0 = blockIdx.x * 64 + lane;
  bool valid = n0 < N_NODES;
  int n = valid ? n0 : (N_NODES - 1);
  float xv[16];
  {
    const float4* x4 = (const float4*)(x + (size_t)n * 16);
#pragma unroll
    for (int i = 0; i < 4; ++i) {
      float4 q = x4[i];
      xv[4 * i] = q.x; xv[4 * i + 1] = q.y; xv[4 * i + 2] = q.z; xv[4 * i + 3] = q.w;
    }
  }
  const float* Af = fac + FAC_A + h * 256;
  const float* Bf = fac + FAC_B + h * 96;
  const float* cf = fac + FAC_C + h * 16;
  const float* df = fac + FAC_D + h * 16;
  const float* ff = fac + FAC_F + h * 6;
  const float  gf = fac[FAC_G + h];
  float va[16];   // A^T x_dst + d_h
#pragma unroll
  for (int g = 0; g < 16; ++g) {
    float a = df[g];
#pragma unroll
    for (int f = 0; f < 16; ++f) a = fmaf(xv[f], Af[f * 16 + g], a);
    va[g] = a;
  }
  float ve[6];    // B^T x_dst + f_h
#pragma unroll
  for (int j = 0; j < 6; ++j) {
    float a = ff[j];
#pragma unroll
    for (int f = 0; f < 16; ++f) a = fmaf(xv[f], Bf[f * 6 + j], a);
    ve[j] = a;
  }
  float v22 = gf;
#pragma unroll
  for (int f = 0; f < 16; ++f) v22 = fmaf(xv[f], cf[f], v22);

  int dg = valid ? cursor[n0] : 0;
  if (dg > CAP) dg = CAP;
  float m = -1e30f, den = 0.f;
  float Sx[16];
  float Sa[6];
#pragma unroll
  for (int f = 0; f < 16; ++f) Sx[f] = 0.f;
#pragma unroll
  for (int j = 0; j < 6; ++j) Sa[j] = 0.f;
  for (int q2 = 0; q2 < dg; ++q2) {
    const float* er = erec + ((size_t)n0 * CAP + q2) * 8;
    int4 ra = *(const int4*)er;
    float4 rb = *(const float4*)(er + 4);
    int s = ra.x;
    const float4* xs4 = (const float4*)(x + (size_t)s * 16);
    float4 a0 = xs4[0], a1 = xs4[1], a2 = xs4[2], a3 = xs4[3];
    float xs[16] = {a0.x, a0.y, a0.z, a0.w, a1.x, a1.y, a1.z, a1.w,
                    a2.x, a2.y, a2.z, a2.w, a3.x, a3.y, a3.z, a3.w};
    float eav[6] = {__int_as_float(ra.y), __int_as_float(ra.z),
                    __int_as_float(ra.w), rb.x, rb.y, rb.z};
    float alpha = v22;
#pragma unroll
    for (int f = 0; f < 16; ++f) alpha = fmaf(va[f], xs[f], alpha);
#pragma unroll
    for (int j = 0; j < 6; ++j) alpha = fmaf(ve[j], eav[j], alpha);
    alpha *= RS;
    float nm = fmaxf(m, alpha);
    float sc = __expf(m - nm);
    float w = __expf(alpha - nm);
    den = den * sc + w;
#pragma unroll
    for (int f = 0; f < 16; ++f) Sx[f] = fmaf(Sx[f], sc, w * xs[f]);
#pragma unroll
    for (int j = 0; j < 6; ++j) Sa[j] = fmaf(Sa[j], sc, w * eav[j]);
    m = nm;
  }
  {
    float inv = 1.f / (den + 1e-16f);
    float outv[24];
#pragma unroll
    for (int f = 0; f < 16; ++f) outv[f] = Sx[f] * inv;
#pragma unroll
    for (int j = 0; j < 6; ++j) outv[16 + j] = Sa[j] * inv;
    outv[22] = den * inv;   // sum of attn (1 unless isolated node)
    outv[23] = 0.f;
    uint pk[12];
#pragma unroll
    for (int i = 0; i < 12; ++i)
      pk[i] = (uint)f2bf(outv[2 * i]) | ((uint)f2bf(outv[2 * i + 1]) << 16);
    int4* vp = (int4*)(Vls + lane * 136 + h * 24);
    int4 s0, s1, s2;
    s0.x = (int)pk[0]; s0.y = (int)pk[1]; s0.z = (int)pk[2]; s0.w = (int)pk[3];
    s1.x = (int)pk[4]; s1.y = (int)pk[5]; s1.z = (int)pk[6]; s1.w = (int)pk[7];
    s2.x = (int)pk[8]; s2.y = (int)pk[9]; s2.z = (int)pk[10]; s2.w = (int)pk[11];
    vp[0] = s0; vp[1] = s1; vp[2] = s2;
  }
  if (wid == 0) {
    // skip rows [96..127]: bf16 x (from registers), const 1.0, zeros
    uint pk[8];
#pragma unroll
    for (int i = 0; i < 8; ++i)
      pk[i] = (uint)f2bf(xv[2 * i]) | ((uint)f2bf(xv[2 * i + 1]) << 16);
    int4* vp = (int4*)(Vls + lane * 136 + 96);
    int4 s0, s1, s2, s3;
    s0.x = (int)pk[0]; s0.y = (int)pk[1]; s0.z = (int)pk[2]; s0.w = (int)pk[3];
    s1.x = (int)pk[4]; s1.y = (int)pk[5]; s1.z = (int)pk[6]; s1.w = (int)pk[7];
    s2.x = (int)0x3F80u; s2.y = 0; s2.z = 0; s2.w = 0;   // bf16(1.0) + zeros
    s3.x = 0; s3.y = 0; s3.z = 0; s3.w = 0;
    vp[0] = s0; vp[1] = s1; vp[2] = s2; vp[3] = s3;
  }
  __syncthreads();

  // ===== layer 1 GEMM: wave handles 16 nodes x 64 cols (4 C-tiles) =====
  int col15 = lane & 15, quad = lane >> 4;
  f32x4 acc[4];
#pragma unroll
  for (int T = 0; T < 4; ++T) acc[T] = (f32x4){0.f, 0.f, 0.f, 0.f};
#pragma unroll
  for (int kk = 0; kk < 4; ++kk) {
    int k0 = kk * 32;
    short8 a = *(const short8*)(Vls + (wid * 16 + col15) * 136 + k0 + quad * 8);
#pragma unroll
    for (int T = 0; T < 4; ++T) {
      short8 bfr = *(const short8*)(Wcs + (T * 16 + col15) * 136 + k0 + quad * 8);
      acc[T] = __builtin_amdgcn_mfma_f32_16x16x32_bf16(a, bfr, acc[T], 0, 0, 0);
    }
  }
#pragma unroll
  for (int T = 0; T < 4; ++T) {
#pragma unroll
    for (int r = 0; r < 4; ++r) {
      int nloc = wid * 16 + quad * 4 + r;
      int c = T * 16 + col15;
      h1b[nloc * 72 + c] = f2bf(fmaxf(acc[T][r], 0.f));
    }
  }
  __syncthreads();
  // ===== layer 2 GEMM: h2[16 nodes x 16] per wave, K=64 -> 2 mfma =====
  float b2v = b2[col15];
  f32x4 acc2 = (f32x4){0.f, 0.f, 0.f, 0.f};
#pragma unroll
  for (int kk = 0; kk < 2; ++kk) {
    int k0 = kk * 32;
    short8 a2 = *(const short8*)(h1b + (wid * 16 + col15) * 72 + k0 + quad * 8);
    short8 bf2 = *(const short8*)(W2ts + col15 * 72 + k0 + quad * 8);
    acc2 = __builtin_amdgcn_mfma_f32_16x16x32_bf16(a2, bf2, acc2, 0, 0, 0);
  }
#pragma unroll
  for (int r = 0; r < 4; ++r) {
    int nloc = wid * 16 + quad * 4 + r;
    h2s[nloc * 17 + col15] = fmaxf(acc2[r] + b2v, 0.f);
  }
  __syncthreads();
  // ===== layer 3 + softmax: one thread per node =====
  if (tid < 64) {
    int n2 = blockIdx.x * 64 + tid;
    if (n2 < N_NODES) {
      float hv[16];
#pragma unroll
      for (int j = 0; j < 16; ++j) hv[j] = h2s[tid * 17 + j];
      float lg[6];
      float mx = -1e30f;
#pragma unroll
      for (int o = 0; o < 6; ++o) {
        float a = b3[o];
#pragma unroll
        for (int j = 0; j < 16; ++j) a = fmaf(hv[j], W3[j * 6 + o], a);
        lg[o] = a; mx = fmaxf(mx, a);
      }
      float s = 0.f;
#pragma unroll
      for (int o = 0; o < 6; ++o) { lg[o] = __expf(lg[o] - mx); s += lg[o]; }
      float inv = 1.f / s;
      float2* o2 = (float2*)(out + (size_t)n2 * 6);
      o2[0] = make_float2(lg[0] * inv, lg[1] * inv);
      o2[1] = make_float2(lg[2] * inv, lg[3] * inv);
      o2[2] = make_float2(lg[4] * inv, lg[5] * inv);
    }
  }
}

extern "C" void kernel_launch(void* const* d_in, const int* in_sizes, int n_in,
                              void* d_out, int out_size, void* d_ws, size_t ws_size,
                              hipStream_t stream) {
  const float* x     = (const float*)d_in[0];
  const int*   ei    = (const int*)d_in[1];
  const float* ea    = (const float*)d_in[2];
  const float* Wq    = (const float*)d_in[3];
  const float* bq    = (const float*)d_in[4];
  const float* Wk    = (const float*)d_in[5];
  const float* bk    = (const float*)d_in[6];
  const float* Wv    = (const float*)d_in[7];
  const float* bv    = (const float*)d_in[8];
  const float* We    = (const float*)d_in[9];
  const float* Wskip = (const float*)d_in[10];
  const float* bskip = (const float*)d_in[11];
  const float* W1    = (const float*)d_in[12];
  const float* b1    = (const float*)d_in[13];
  const float* W2    = (const float*)d_in[14];
  const float* b2    = (const float*)d_in[15];
  const float* W3    = (const float*)d_in[16];
  const float* b3    = (const float*)d_in[17];
  float* out = (float*)d_out;
  (void)in_sizes; (void)n_in; (void)out_size; (void)ws_size;

  char* ws = (char*)d_ws;
  size_t off = 0;
  auto alloc = [&](size_t bytes) {
    void* p = ws + off;
    off = (off + bytes + 255) & ~(size_t)255;
    return p;
  };
  float*  fac    = (float*)alloc(FAC_TOTAL * 4);
  ushort* Wct    = (ushort*)alloc(64 * WC_K * 2);
  int*    cursor = (int*)alloc(N_NODES * 4);
  ushort* W2tg   = (ushort*)alloc(16 * 64 * 2);
  float*  erec   = (float*)alloc((size_t)N_NODES * CAP * 8 * 4);  // 32B records

  hipMemsetAsync(cursor, 0, N_NODES * 4, stream);
  prep_kernel<<<P_TOTAL, 256, 0, stream>>>(
      Wq, Wk, We, bq, bk, fac, Wv, bv, Wskip, bskip, W1, b1, Wct, W2, W2tg,
      ei, ea, cursor, erec);
  fused_kernel<<<391, 256, 0, stream>>>(x, fac, erec, cursor, Wct, W2tg,
                                        b2, W3, b3, out);
}